// Round 7
// baseline (197.191 us; speedup 1.0000x reference)
//
#include <hip/hip_runtime.h>
#include <cstddef>
#include <cstdint>

#define T_DIM 2048
#define E_DIM 1024
#define M_DIM 4096   // T*B rows, row index = t*2 + b

typedef __attribute__((ext_vector_type(8))) short short8;      // 8 fp16 bit-patterns
typedef __attribute__((ext_vector_type(8))) _Float16 half8;    // mfma f16 A/B (x32)
typedef __attribute__((ext_vector_type(4))) _Float16 half4;    // mfma f16 A/B (x16)
typedef __attribute__((ext_vector_type(4))) float f32x4;       // mfma C/D

__device__ __forceinline__ short f16_bits(float v) {
  return __builtin_bit_cast(short, (_Float16)v);
}
__device__ __forceinline__ unsigned int pk2(float a, float b) {
  return __builtin_bit_cast(unsigned int, __builtin_amdgcn_cvt_pkrtz(a, b));
}
__device__ __forceinline__ half8 h8(short8 s) { return __builtin_bit_cast(half8, s); }

// async global->LDS, 16B per lane; LDS dest = wave-uniform base + lane*16
__device__ __forceinline__ void gl_lds16(const short* g, const short* l) {
  __builtin_amdgcn_global_load_lds(
      (const __attribute__((address_space(1))) unsigned int*)g,
      (__attribute__((address_space(3))) unsigned int*)l, 16, 0, 0);
}

// ---------------------------------------------------------------------------
// fp32 -> fp16 (RNE). blocks: [0,4096) x ; then 1024 each wq, wk, wv, wo.
// ---------------------------------------------------------------------------
__global__ __launch_bounds__(256) void convert_all(
    const float* __restrict__ x, const float* __restrict__ wq,
    const float* __restrict__ wk, const float* __restrict__ wv,
    const float* __restrict__ wo,
    short* __restrict__ xh, short* __restrict__ wqh, short* __restrict__ wkh,
    short* __restrict__ wvh, short* __restrict__ woh)
{
  const int bid = blockIdx.x;
  const float* in; short* hi; int base;
  if (bid < 4096)      { in = x;  hi = xh;  base = 0;    }
  else if (bid < 5120) { in = wq; hi = wqh; base = 4096; }
  else if (bid < 6144) { in = wk; hi = wkh; base = 5120; }
  else if (bid < 7168) { in = wv; hi = wvh; base = 6144; }
  else                 { in = wo; hi = woh; base = 7168; }
  const int i = (bid - base) * 256 + threadIdx.x;     // float4 index
  float4 v = ((const float4*)in)[i];
  uint2 p;
  p.x = (unsigned short)f16_bits(v.x) | ((unsigned int)(unsigned short)f16_bits(v.y) << 16);
  p.y = (unsigned short)f16_bits(v.z) | ((unsigned int)(unsigned short)f16_bits(v.w) << 16);
  ((uint2*)hi)[i] = p;
}

// ---------------------------------------------------------------------------
// Fused QKV GEMM, fp16, BK=64. C = (A @ W^T + b) * scale.
// r7 change: Q/K epilogue now goes through an LDS transpose (Tb[64][136],
// 272B row stride: 16B-aligned for b128 reads, 2-way bank alias = free) and
// emits 8 coalesced short8 stores/lane instead of 64 scattered 2B stores
// (4x32B segments each). Within-session evidence: r2->r3 A/B on the V
// output showed the transpose path ~4us faster than direct scatter.
// V (sel==2) epilogue unchanged (proven d-major transpose path).
// ---------------------------------------------------------------------------
__global__ __launch_bounds__(256) void gemm_qkv(
    const short* __restrict__ xh,
    const short* __restrict__ wqh, const short* __restrict__ wkh,
    const short* __restrict__ wvh,
    const float* __restrict__ bq, const float* __restrict__ bk,
    const float* __restrict__ bv,
    short* __restrict__ qo, short* __restrict__ ko, short* __restrict__ vto)
{
  __shared__ __align__(16) short smem[128 * 64 * 2];   // Ah | Wh ; Tb overlays
  short* Ah = smem;
  short* Wh = smem + 8192;
  const int tid = threadIdx.x;
  const int lane = tid & 63;
  const int w = tid >> 6;
  const int quad = lane >> 4;
  const int l15 = lane & 15;
  const int sel = blockIdx.x >> 3;
  const int n0 = (blockIdx.x & 7) * 128;
  const int m0 = blockIdx.y * 128;

  const short* wsel = sel == 0 ? wqh : sel == 1 ? wkh : wvh;
  const float* bias = sel == 0 ? bq : sel == 1 ? bk : bv;
  const float scale = sel == 0 ? 0.125f * 1.44269504088896f : 1.0f;

  const short* gsrc = (w < 2) ? xh : wsel;
  short* lbuf = (w < 2) ? Ah : Wh;
  const int rbase = (w < 2) ? m0 : n0;
  const int lrow8 = lane >> 3;
  const int gph8 = lane & 7;
  const int kg = (gph8 - lrow8) & 7;    // global k-group this lane stages

  f32x4 zero = {0.f, 0.f, 0.f, 0.f};
  f32x4 acc[4][4];
#pragma unroll
  for (int i = 0; i < 4; ++i)
#pragma unroll
    for (int j = 0; j < 4; ++j) acc[i][j] = zero;

  const int wm = w & 1, wn = w >> 1;

  for (int k0 = 0; k0 < E_DIM; k0 += 64) {
    __syncthreads();
#pragma unroll
    for (int jj = 0; jj < 8; ++jj) {
      int j = (w & 1) * 8 + jj;       // 16 staging insts per matrix, 2 waves
      int r = j * 8 + lrow8;          // 0..127
      gl_lds16(gsrc + (size_t)(rbase + r) * E_DIM + k0 + kg * 8, lbuf + j * 512);
    }
    __syncthreads();
#pragma unroll
    for (int ks = 0; ks < 2; ++ks) {
      short8 ahf[4];
#pragma unroll
      for (int i = 0; i < 4; ++i) {
        int r = wm * 64 + i * 16 + l15;
        ahf[i] = *(const short8*)&Ah[r * 64 + ((ks * 4 + quad + r) & 7) * 8];
      }
#pragma unroll
      for (int j = 0; j < 4; ++j) {
        int r = wn * 64 + j * 16 + l15;
        short8 bhf = *(const short8*)&Wh[r * 64 + ((ks * 4 + quad + r) & 7) * 8];
#pragma unroll
        for (int i = 0; i < 4; ++i)
          acc[i][j] = __builtin_amdgcn_mfma_f32_16x16x32_f16(h8(ahf[i]), h8(bhf), acc[i][j], 0, 0, 0);
      }
    }
  }

  if (sel < 2) {
    // ---- Q/K epilogue via LDS transpose: Tb[64][136] per R-half ----
    short* Tb = smem;
    short* dst = sel == 0 ? qo : ko;
#pragma unroll
    for (int R = 0; R < 2; ++R) {
      __syncthreads();               // prev-phase LDS reads / stores drained
      if (wm == R) {                 // waves {R, R+2} hold this row-half
#pragma unroll
        for (int j = 0; j < 4; ++j) {
          const int c = wn * 64 + j * 16 + l15;
          const float bb = bias[n0 + c];
#pragma unroll
          for (int i = 0; i < 4; ++i)
#pragma unroll
            for (int reg = 0; reg < 4; ++reg) {
              const int r = i * 16 + quad * 4 + reg;   // 0..63 (bijective)
              Tb[r * 136 + c] = f16_bits((acc[i][j][reg] + bb) * scale);
            }
        }
      }
      __syncthreads();
      // read rows, store coalesced: 16B per lane, 2x128B segments per inst
#pragma unroll
      for (int rr = 0; rr < 4; ++rr) {
        const int row = w * 16 + rr * 4 + quad;        // 0..63
        short8 v = *(const short8*)&Tb[row * 136 + l15 * 8];
        const int gm = m0 + R * 64 + row;
        const int t = gm >> 1, bI = gm & 1;
        const int cc = l15 * 8;
        const int hh = (n0 + cc) >> 6;
        const int dd = cc & 63;
        *(short8*)&dst[((size_t)(bI * 16 + hh) * T_DIM + t) * 64 + dd] = v;
      }
    }
  } else {
    short* Tb = smem;   // 64 * 128 * 2B = 16KB
    const int by = blockIdx.y;
#pragma unroll
    for (int R = 0; R < 2; ++R) {
      __syncthreads();
      if (wn == R) {
#pragma unroll
        for (int j = 0; j < 4; ++j) {
          const int nl = j * 16 + l15;
          const int gc = n0 + R * 64 + nl;
          const float bb = bias[gc];
#pragma unroll
          for (int i = 0; i < 4; ++i) {
            const int tp = wm * 32 + i * 8 + quad * 2;        // t' base (even)
            unsigned int lo = pk2(acc[i][j][0] + bb, acc[i][j][2] + bb);
            unsigned int hi = pk2(acc[i][j][1] + bb, acc[i][j][3] + bb);
            const int g0 = tp >> 3;
            const int sub = tp & 7;
            *(unsigned int*)&Tb[nl * 128 + ((g0 + nl) & 15) * 8 + sub] = lo;
            *(unsigned int*)&Tb[nl * 128 + ((g0 + 8 + nl) & 15) * 8 + sub] = hi;
          }
        }
      }
      __syncthreads();
#pragma unroll
      for (int ii = 0; ii < 4; ++ii) {
        const int n = w * 16 + ii * 4 + quad;
        const int g = (l15 - n) & 15;
        short8 vvec = *(const short8*)&Tb[n * 128 + l15 * 8];
        const int gc = n0 + R * 64 + n;
        const int h = gc >> 6, d = gc & 63;
        const int b = g >> 3;
        const int t = by * 64 + (g & 7) * 8;
        *(short8*)&vto[((size_t)(b * 16 + h) * 64 + d) * T_DIM + t] = vvec;
      }
    }
  }
}

// ---------------------------------------------------------------------------
// Output projection v2 (r6, measured-good): 64x128 tiles, grid (8,64)=512
// blocks (2/CU), 256 thr, serial K=1024, direct bias+fp32 epilogue.
// ---------------------------------------------------------------------------
__global__ __launch_bounds__(256) void gemm_out_v2(
    const short* __restrict__ attn, const short* __restrict__ woh,
    const float* __restrict__ bo, float* __restrict__ out)
{
  __shared__ __align__(16) short smem[12288];   // Ah 64x64 (8KB) | Wh 128x64 (16KB)
  short* Ah = smem;
  short* Wh = smem + 4096;
  const int tid = threadIdx.x;
  const int lane = tid & 63;
  const int w = tid >> 6;          // 0..3 = wn (4-way N split)
  const int quad = lane >> 4;
  const int l15 = lane & 15;
  const int n0 = blockIdx.x * 128;
  const int m0 = blockIdx.y * 64;

  const int lrow8 = lane >> 3;
  const int gph8 = lane & 7;
  const int kg = (gph8 - lrow8) & 7;

  f32x4 zero = {0.f, 0.f, 0.f, 0.f};
  f32x4 acc[4][2];
#pragma unroll
  for (int i = 0; i < 4; ++i)
#pragma unroll
    for (int j = 0; j < 2; ++j) acc[i][j] = zero;

  for (int k0 = 0; k0 < E_DIM; k0 += 64) {
    __syncthreads();
    if (w < 2) {                    // stage A: 8 row-groups, 4 per wave
#pragma unroll
      for (int jj = 0; jj < 4; ++jj) {
        int j = w * 4 + jj;
        int r = j * 8 + lrow8;      // 0..63
        gl_lds16(attn + (size_t)(m0 + r) * E_DIM + k0 + kg * 8, Ah + j * 512);
      }
    } else {                        // stage W: 16 row-groups, 8 per wave
#pragma unroll
      for (int jj = 0; jj < 8; ++jj) {
        int j = (w - 2) * 8 + jj;
        int r = j * 8 + lrow8;      // 0..127
        gl_lds16(woh + (size_t)(n0 + r) * E_DIM + k0 + kg * 8, Wh + j * 512);
      }
    }
    __syncthreads();
#pragma unroll
    for (int ks = 0; ks < 2; ++ks) {
      short8 ahf[4];
#pragma unroll
      for (int i = 0; i < 4; ++i) {
        int r = i * 16 + l15;       // all 64 A-rows
        ahf[i] = *(const short8*)&Ah[r * 64 + ((ks * 4 + quad + r) & 7) * 8];
      }
#pragma unroll
      for (int j = 0; j < 2; ++j) {
        int r = w * 32 + j * 16 + l15;   // this wave's 32 W-rows
        short8 bhf = *(const short8*)&Wh[r * 64 + ((ks * 4 + quad + r) & 7) * 8];
#pragma unroll
        for (int i = 0; i < 4; ++i)
          acc[i][j] = __builtin_amdgcn_mfma_f32_16x16x32_f16(h8(ahf[i]), h8(bhf), acc[i][j], 0, 0, 0);
      }
    }
  }

#pragma unroll
  for (int j = 0; j < 2; ++j) {
    const int gc = n0 + w * 32 + j * 16 + l15;
    const float bb = bo[gc];
#pragma unroll
    for (int i = 0; i < 4; ++i)
#pragma unroll
      for (int reg = 0; reg < 4; ++reg) {
        const int gm = m0 + i * 16 + quad * 4 + reg;
        out[(size_t)gm * E_DIM + gc] = acc[i][j][reg] + bb;
      }
  }
}

// ---------------------------------------------------------------------------
// Flash attention v5 (round-2/6 verbatim, measured 51.3-52.0 us) — d-major V,
// ring3, vmcnt(4) waits, XCD remap, setprio. Counters pin this structure:
// MfmaUtil 38 + VALUBusy 35 from 2 waves/SIMD (grid-locked 2 blocks/CU);
// all QBLK/ring/layout neighbors measured worse (r1,r3,r4,r5). DO NOT TOUCH.
// ---------------------------------------------------------------------------
__global__ __launch_bounds__(256, 2) void attn_mfma(
    const short* __restrict__ q, const short* __restrict__ k,
    const short* __restrict__ vt, short* __restrict__ attn)
{
  __shared__ __align__(16) short SMEM[32768];   // 64 KB
  __shared__ float l_red[4][128];
  short* Qs = SMEM;            // 16 KB, dead after qa load
  short* KV = SMEM + 8192;     // ring[3] x wave[4] x (K 1024 + V 1024 shorts)

  const int tid = threadIdx.x;
  const int lane = tid & 63;
  const int w = tid >> 6;
  const int quad = lane >> 4;
  const int l15 = lane & 15;

  // XCD-aware remap: dispatch-linear id fid -> XCD fid%8.
  const int fid = blockIdx.y * 16 + blockIdx.x;
  const int bhid = fid & 31;
  const int t0 = (fid >> 5) * 128;
  const int b = bhid >> 4, h = bhid & 15;

  const short* qb = q + (size_t)bhid * T_DIM * 64;
  const short* kb = k + (size_t)bhid * T_DIM * 64;
  const short* vb = vt + (size_t)bhid * 64 * T_DIM;

  const int lrow8 = lane >> 3;
  const int gph8 = lane & 7;

  // ---- stage Q tile [128][64] ----
#pragma unroll
  for (int jj = 0; jj < 4; ++jj) {
    int j = w * 4 + jj;
    int r = j * 8 + lrow8;
    int gl = (gph8 - (r >> 1)) & 7;
    gl_lds16(qb + (size_t)(t0 + r) * 64 + gl * 8, Qs + j * 512);
  }

  // ---- stage K/V chunks 0,1 into rings 0,1 (wave-private slices) ----
  const int kg = (gph8 - lrow8) & 7;
  const int vd = lane >> 1, vh = lane & 1;
#pragma unroll
  for (int c0 = 0; c0 < 2; ++c0) {
    short* slot = KV + c0 * 8192 + w * 2048;
    const int sg = c0 * 64 + w * 16;
    gl_lds16(kb + (size_t)(sg + lrow8) * 64 + kg * 8, slot);
    gl_lds16(kb + (size_t)(sg + lrow8 + 8) * 64 + kg * 8, slot + 512);
    gl_lds16(vb + (size_t)vd * T_DIM + sg + vh * 8, slot + 1024);
    gl_lds16(vb + (size_t)(vd + 32) * T_DIM + sg + vh * 8, slot + 1536);
  }
  __syncthreads();

  // ---- register-cache Q B-fragments ----
  short8 qa[8][2];
#pragma unroll
  for (int qbk = 0; qbk < 8; ++qbk)
#pragma unroll
    for (int st = 0; st < 2; ++st) {
      int r = qbk * 16 + l15;
      int idx = r * 64 + (((st * 4 + quad) + (r >> 1)) & 7) * 8;
      qa[qbk][st] = *(const short8*)&Qs[idx];
    }

  f32x4 zero = {0.f, 0.f, 0.f, 0.f};
  f32x4 acc[4][8];               // [dblk][qbk] : O^T partial over own s-subset
  float l_part[8];
#pragma unroll
  for (int d = 0; d < 4; ++d)
#pragma unroll
    for (int qb2 = 0; qb2 < 8; ++qb2) acc[d][qb2] = zero;
#pragma unroll
  for (int i = 0; i < 8; ++i) l_part[i] = 0.f;

  for (int c = 0; c < 32; ++c) {
    if (c >= 2) {
      if (c == 31) __builtin_amdgcn_s_waitcnt(0x0F70);   // vmcnt(0)
      else         __builtin_amdgcn_s_waitcnt(0x0F74);   // vmcnt(4)
    }
    const short* slot = KV + (c % 3) * 8192 + w * 2048;

    short8 kf[2];
#pragma unroll
    for (int st = 0; st < 2; ++st)
      kf[st] = *(const short8*)&slot[l15 * 64 + (((st * 4 + quad) + l15) & 7) * 8];
    uint2 vfu[4];
#pragma unroll
    for (int dblk = 0; dblk < 4; ++dblk)
      vfu[dblk] = *(const uint2*)&slot[1024 + (dblk * 16 + l15) * 16 + quad * 4];

    if (c < 30) {
      short* nslot = KV + ((c + 2) % 3) * 8192 + w * 2048;
      const int sg = (c + 2) * 64 + w * 16;
      gl_lds16(kb + (size_t)(sg + lrow8) * 64 + kg * 8, nslot);
      gl_lds16(kb + (size_t)(sg + lrow8 + 8) * 64 + kg * 8, nslot + 512);
      gl_lds16(vb + (size_t)vd * T_DIM + sg + vh * 8, nslot + 1024);
      gl_lds16(vb + (size_t)(vd + 32) * T_DIM + sg + vh * 8, nslot + 1536);
    }

    __builtin_amdgcn_s_setprio(1);
    uint2 pb[8];
#pragma unroll
    for (int qbk = 0; qbk < 8; ++qbk) {
      f32x4 s = zero;
      s = __builtin_amdgcn_mfma_f32_16x16x32_f16(h8(kf[0]), h8(qa[qbk][0]), s, 0, 0, 0);
      s = __builtin_amdgcn_mfma_f32_16x16x32_f16(h8(kf[1]), h8(qa[qbk][1]), s, 0, 0, 0);
      float p0 = __builtin_amdgcn_exp2f(s[0]);
      float p1 = __builtin_amdgcn_exp2f(s[1]);
      float p2 = __builtin_amdgcn_exp2f(s[2]);
      float p3 = __builtin_amdgcn_exp2f(s[3]);
      l_part[qbk] += (p0 + p1) + (p2 + p3);
      pb[qbk].x = pk2(p0, p1);
      pb[qbk].y = pk2(p2, p3);
    }

#pragma unroll
    for (int dblk = 0; dblk < 4; ++dblk) {
      half4 va = __builtin_bit_cast(half4, vfu[dblk]);
#pragma unroll
      for (int qbk = 0; qbk < 8; ++qbk)
        acc[dblk][qbk] = __builtin_amdgcn_mfma_f32_16x16x16f16(
            va, __builtin_bit_cast(half4, pb[qbk]), acc[dblk][qbk], 0, 0, 0);
    }
    __builtin_amdgcn_s_setprio(0);
  }

  // ---- l reduce over quads, publish per-wave ----
#pragma unroll
  for (int qbk = 0; qbk < 8; ++qbk) {
    float l = l_part[qbk];
    l += __shfl_xor(l, 16);
    l += __shfl_xor(l, 32);
    if (quad == 0) l_red[w][qbk * 16 + l15] = l;
  }

  // ---- pairwise O reduce via 64 KB LDS scratch (overlays Qs+KV) ----
  f32x4* Osc = (f32x4*)SMEM;     // regions of 1024/2048 f32x4
  __syncthreads();               // all waves out of the main loop
  if (w & 1) {                   // w1 -> region0, w3 -> region1
    f32x4* dst = Osc + (w >> 1) * 2048;
#pragma unroll
    for (int dblk = 0; dblk < 4; ++dblk)
#pragma unroll
      for (int qbk = 0; qbk < 8; ++qbk)
        dst[(dblk * 8 + qbk) * 64 + lane] = acc[dblk][qbk];
  }
  __syncthreads();
  if (!(w & 1)) {                // w0 += region0 (all dblk), w2 += region1
    f32x4* src = Osc + (w >> 1) * 2048;
#pragma unroll
    for (int dblk = 0; dblk < 4; ++dblk)
#pragma unroll
      for (int qbk = 0; qbk < 8; ++qbk) {
        f32x4 t = src[(dblk * 8 + qbk) * 64 + lane];
        acc[dblk][qbk][0] += t[0]; acc[dblk][qbk][1] += t[1];
        acc[dblk][qbk][2] += t[2]; acc[dblk][qbk][3] += t[3];
      }
  }
  __syncthreads();
  // swap-publish: w2 gives its dblk 0,1 to w0; w0 gives its dblk 2,3 to w2
  if (w == 2) {
#pragma unroll
    for (int d2 = 0; d2 < 2; ++d2)
#pragma unroll
      for (int qbk = 0; qbk < 8; ++qbk)
        Osc[(d2 * 8 + qbk) * 64 + lane] = acc[d2][qbk];
  }
  if (w == 0) {
#pragma unroll
    for (int d2 = 0; d2 < 2; ++d2)
#pragma unroll
      for (int qbk = 0; qbk < 8; ++qbk)
        Osc[1024 + (d2 * 8 + qbk) * 64 + lane] = acc[2 + d2][qbk];
  }
  __syncthreads();
  if (w == 0) {                  // stores dblk 0,1
#pragma unroll
    for (int qbk = 0; qbk < 8; ++qbk) {
      const int qq = qbk * 16 + l15;
      const float lsum = l_red[0][qq] + l_red[1][qq] + l_red[2][qq] + l_red[3][qq];
      const float inv = 1.f / lsum;
      const int t = t0 + qq;
      const size_t mrow = (size_t)(t * 2 + b) * E_DIM;
#pragma unroll
      for (int d2 = 0; d2 < 2; ++d2) {
        f32x4 t4 = Osc[(d2 * 8 + qbk) * 64 + lane];
        uint2 ov;
        ov.x = pk2((acc[d2][qbk][0] + t4[0]) * inv, (acc[d2][qbk][1] + t4[1]) * inv);
        ov.y = pk2((acc[d2][qbk][2] + t4[2]) * inv, (acc[d2][qbk][3] + t4[3]) * inv);
        *(uint2*)&attn[mrow + h * 64 + d2 * 16 + quad * 4] = ov;
      }
    }
  }
  if (w == 2) {                  // stores dblk 2,3
#pragma unroll
    for (int qbk = 0; qbk < 8; ++qbk) {
      const int qq = qbk * 16 + l15;
      const float lsum = l_red[0][qq] + l_red[1][qq] + l_red[2][qq] + l_red[3][qq];
      const float inv = 1.f / lsum;
      const int t = t0 + qq;
      const size_t mrow = (size_t)(t * 2 + b) * E_DIM;
#pragma unroll
      for (int d2 = 0; d2 < 2; ++d2) {
        f32x4 t4 = Osc[1024 + (d2 * 8 + qbk) * 64 + lane];
        uint2 ov;
        ov.x = pk2((acc[2 + d2][qbk][0] + t4[0]) * inv, (acc[2 + d2][qbk][1] + t4[1]) * inv);
        ov.y = pk2((acc[2 + d2][qbk][2] + t4[2]) * inv, (acc[2 + d2][qbk][3] + t4[3]) * inv);
        *(uint2*)&attn[mrow + h * 64 + (2 + d2) * 16 + quad * 4] = ov;
      }
    }
  }
}

// ---------------------------------------------------------------------------
extern "C" void kernel_launch(void* const* d_in, const int* in_sizes, int n_in,
                              void* d_out, int out_size, void* d_ws, size_t ws_size,
                              hipStream_t stream)
{
  const float* x  = (const float*)d_in[0];
  const float* wq = (const float*)d_in[1];
  const float* bq = (const float*)d_in[2];
  const float* wk = (const float*)d_in[3];
  const float* bk = (const float*)d_in[4];
  const float* wv = (const float*)d_in[5];
  const float* bv = (const float*)d_in[6];
  const float* wo = (const float*)d_in[7];
  const float* bo = (const float*)d_in[8];
  float* out = (float*)d_out;

  short* ws = (short*)d_ws;
  const size_t M4 = (size_t)M_DIM * E_DIM;   // 4M elems
  const size_t M1 = (size_t)E_DIM * E_DIM;   // 1M elems
  short* aws  = ws;          // attn out fp16, live until gemm_out
  short* woh  = aws + M4;    // wo fp16, live until gemm_out
  short* xh   = woh + M1;
  short* wqh  = xh + M4;
  short* wkh  = wqh + M1;
  short* wvh  = wkh + M1;
  short* qws  = wvh + M1;
  short* kws  = qws + M4;
  short* vtws = kws + M4;    // end = 24M shorts = 48 MB

  convert_all<<<8192, 256, 0, stream>>>(x, wq, wk, wv, wo, xh, wqh, wkh, wvh, woh);
  gemm_qkv<<<dim3(24, 32), 256, 0, stream>>>(xh, wqh, wkh, wvh, bq, bk, bv,
                                             qws, kws, vtws);
  attn_mfma<<<dim3(16, 32), 256, 0, stream>>>(qws, kws, vtws, aws);
  gemm_out_v2<<<dim3(8, 64), 256, 0, stream>>>(aws, woh, bo, out);
}

// Round 8
// 186.121 us; speedup vs baseline: 1.0595x; 1.0595x over previous
//
#include <hip/hip_runtime.h>
#include <cstddef>
#include <cstdint>

#define T_DIM 2048
#define E_DIM 1024
#define M_DIM 4096   // T*B rows, row index = t*2 + b

typedef __attribute__((ext_vector_type(8))) short short8;      // 8 fp16 bit-patterns
typedef __attribute__((ext_vector_type(8))) _Float16 half8;    // mfma f16 A/B (x32)
typedef __attribute__((ext_vector_type(4))) _Float16 half4;    // mfma f16 A/B (x16)
typedef __attribute__((ext_vector_type(4))) float f32x4;       // mfma C/D

__device__ __forceinline__ short f16_bits(float v) {
  return __builtin_bit_cast(short, (_Float16)v);
}
__device__ __forceinline__ unsigned int pk2(float a, float b) {
  return __builtin_bit_cast(unsigned int, __builtin_amdgcn_cvt_pkrtz(a, b));
}
__device__ __forceinline__ half8 h8(short8 s) { return __builtin_bit_cast(half8, s); }

// async global->LDS, 16B per lane; LDS dest = wave-uniform base + lane*16
__device__ __forceinline__ void gl_lds16(const short* g, const short* l) {
  __builtin_amdgcn_global_load_lds(
      (const __attribute__((address_space(1))) unsigned int*)g,
      (__attribute__((address_space(3))) unsigned int*)l, 16, 0, 0);
}

// ---------------------------------------------------------------------------
// fp32 -> fp16 (RNE). blocks: [0,4096) x ; then 1024 each wq, wk, wv, wo.
// ---------------------------------------------------------------------------
__global__ __launch_bounds__(256) void convert_all(
    const float* __restrict__ x, const float* __restrict__ wq,
    const float* __restrict__ wk, const float* __restrict__ wv,
    const float* __restrict__ wo,
    short* __restrict__ xh, short* __restrict__ wqh, short* __restrict__ wkh,
    short* __restrict__ wvh, short* __restrict__ woh)
{
  const int bid = blockIdx.x;
  const float* in; short* hi; int base;
  if (bid < 4096)      { in = x;  hi = xh;  base = 0;    }
  else if (bid < 5120) { in = wq; hi = wqh; base = 4096; }
  else if (bid < 6144) { in = wk; hi = wkh; base = 5120; }
  else if (bid < 7168) { in = wv; hi = wvh; base = 6144; }
  else                 { in = wo; hi = woh; base = 7168; }
  const int i = (bid - base) * 256 + threadIdx.x;     // float4 index
  float4 v = ((const float4*)in)[i];
  uint2 p;
  p.x = (unsigned short)f16_bits(v.x) | ((unsigned int)(unsigned short)f16_bits(v.y) << 16);
  p.y = (unsigned short)f16_bits(v.z) | ((unsigned int)(unsigned short)f16_bits(v.w) << 16);
  ((uint2*)hi)[i] = p;
}

// ---------------------------------------------------------------------------
// Fused QKV GEMM v3 — 8 waves / 512 threads, 128x128 tile (r7 post-mortem:
// 4-wave version was stall-bound: MfmaUtil 17%, VALU 18%, HBM 13%, Occ 15%
// — staging latency exposed every K-step with too few waves to hide it).
// Per-wave sub-tile 64x32: wm=w&1 (2-way M), wn=w>>1 (4-way N), acc[4][2].
// Staging split 8 ways (4 gl_lds/lane). Waves/CU 12 -> 24 at 3 blocks/CU.
// Q/K epilogue: r6 direct-scatter (r7's LDS-transpose epilogue regressed
// qkv to 60.5us — reverted). V epilogue: proven Tb transpose, re-mapped to
// 8 waves (participants w>>2==R; nl=(wn&1)*32+j*16+l15; readout n=w*8+..).
// ---------------------------------------------------------------------------
__global__ __launch_bounds__(512, 4) void gemm_qkv(
    const short* __restrict__ xh,
    const short* __restrict__ wqh, const short* __restrict__ wkh,
    const short* __restrict__ wvh,
    const float* __restrict__ bq, const float* __restrict__ bk,
    const float* __restrict__ bv,
    short* __restrict__ qo, short* __restrict__ ko, short* __restrict__ vto)
{
  __shared__ __align__(16) short smem[128 * 64 * 2];   // Ah | Wh ; Tb overlays
  short* Ah = smem;
  short* Wh = smem + 8192;
  const int tid = threadIdx.x;
  const int lane = tid & 63;
  const int w = tid >> 6;          // 0..7
  const int quad = lane >> 4;
  const int l15 = lane & 15;
  const int sel = blockIdx.x >> 3;
  const int n0 = (blockIdx.x & 7) * 128;
  const int m0 = blockIdx.y * 128;

  const short* wsel = sel == 0 ? wqh : sel == 1 ? wkh : wvh;
  const float* bias = sel == 0 ? bq : sel == 1 ? bk : bv;
  const float scale = sel == 0 ? 0.125f * 1.44269504088896f : 1.0f;

  const short* gsrc = (w < 4) ? xh : wsel;     // waves 0-3 stage A, 4-7 stage W
  short* lbuf = (w < 4) ? Ah : Wh;
  const int rbase = (w < 4) ? m0 : n0;
  const int lrow8 = lane >> 3;
  const int gph8 = lane & 7;
  const int kg = (gph8 - lrow8) & 7;    // global k-group this lane stages

  f32x4 zero = {0.f, 0.f, 0.f, 0.f};
  f32x4 acc[4][2];
#pragma unroll
  for (int i = 0; i < 4; ++i)
#pragma unroll
    for (int j = 0; j < 2; ++j) acc[i][j] = zero;

  const int wm = w & 1, wn = w >> 1;

  for (int k0 = 0; k0 < E_DIM; k0 += 64) {
    __syncthreads();
#pragma unroll
    for (int jj = 0; jj < 4; ++jj) {
      int j = (w & 3) * 4 + jj;       // 16 groups per matrix, 4 waves each
      int r = j * 8 + lrow8;          // 0..127
      gl_lds16(gsrc + (size_t)(rbase + r) * E_DIM + k0 + kg * 8, lbuf + j * 512);
    }
    __syncthreads();
#pragma unroll
    for (int ks = 0; ks < 2; ++ks) {
      short8 ahf[4];
#pragma unroll
      for (int i = 0; i < 4; ++i) {
        int r = wm * 64 + i * 16 + l15;
        ahf[i] = *(const short8*)&Ah[r * 64 + ((ks * 4 + quad + r) & 7) * 8];
      }
#pragma unroll
      for (int j = 0; j < 2; ++j) {
        int r = wn * 32 + j * 16 + l15;
        short8 bhf = *(const short8*)&Wh[r * 64 + ((ks * 4 + quad + r) & 7) * 8];
#pragma unroll
        for (int i = 0; i < 4; ++i)
          acc[i][j] = __builtin_amdgcn_mfma_f32_16x16x32_f16(h8(ahf[i]), h8(bhf), acc[i][j], 0, 0, 0);
      }
    }
  }

  if (sel < 2) {
#pragma unroll
    for (int j = 0; j < 2; ++j) {
      const int gc = n0 + wn * 32 + j * 16 + l15;
      const float bb = bias[gc];
      const int h = gc >> 6, d = gc & 63;
      short* dst = sel == 0 ? qo : ko;
#pragma unroll
      for (int i = 0; i < 4; ++i)
#pragma unroll
        for (int reg = 0; reg < 4; ++reg) {
          const int gm = m0 + wm * 64 + i * 16 + quad * 4 + reg;
          const float val = (acc[i][j][reg] + bb) * scale;
          const int t = gm >> 1, b = gm & 1;
          dst[((size_t)(b * 16 + h) * T_DIM + t) * 64 + d] = f16_bits(val);
        }
    }
  } else {
    short* Tb = smem;   // 64 * 128 * 2B = 16KB (overlays Ah)
    const int by = blockIdx.y;
#pragma unroll
    for (int R = 0; R < 2; ++R) {
      __syncthreads();
      if ((w >> 2) == R) {           // 4 waves own this n-half (wm x wn&1)
#pragma unroll
        for (int j = 0; j < 2; ++j) {
          const int nl = (wn & 1) * 32 + j * 16 + l15;   // 0..63
          const int gc = n0 + R * 64 + nl;
          const float bb = bias[gc];
#pragma unroll
          for (int i = 0; i < 4; ++i) {
            const int tp = wm * 32 + i * 8 + quad * 2;        // t' base (even)
            unsigned int lo = pk2(acc[i][j][0] + bb, acc[i][j][2] + bb);
            unsigned int hi = pk2(acc[i][j][1] + bb, acc[i][j][3] + bb);
            const int g0 = tp >> 3;
            const int sub = tp & 7;
            *(unsigned int*)&Tb[nl * 128 + ((g0 + nl) & 15) * 8 + sub] = lo;
            *(unsigned int*)&Tb[nl * 128 + ((g0 + 8 + nl) & 15) * 8 + sub] = hi;
          }
        }
      }
      __syncthreads();
#pragma unroll
      for (int ii = 0; ii < 2; ++ii) {
        const int n = w * 8 + ii * 4 + quad;    // 0..63 over 8 waves
        const int g = (l15 - n) & 15;
        short8 vvec = *(const short8*)&Tb[n * 128 + l15 * 8];
        const int gc = n0 + R * 64 + n;
        const int h = gc >> 6, d = gc & 63;
        const int b = g >> 3;
        const int t = by * 64 + (g & 7) * 8;
        *(short8*)&vto[((size_t)(b * 16 + h) * 64 + d) * T_DIM + t] = vvec;
      }
    }
  }
}

// ---------------------------------------------------------------------------
// Output projection v2 (r6, measured-good): 64x128 tiles, grid (8,64)=512
// blocks (2/CU), 256 thr, serial K=1024, direct bias+fp32 epilogue.
// ---------------------------------------------------------------------------
__global__ __launch_bounds__(256) void gemm_out_v2(
    const short* __restrict__ attn, const short* __restrict__ woh,
    const float* __restrict__ bo, float* __restrict__ out)
{
  __shared__ __align__(16) short smem[12288];   // Ah 64x64 (8KB) | Wh 128x64 (16KB)
  short* Ah = smem;
  short* Wh = smem + 4096;
  const int tid = threadIdx.x;
  const int lane = tid & 63;
  const int w = tid >> 6;          // 0..3 = wn (4-way N split)
  const int quad = lane >> 4;
  const int l15 = lane & 15;
  const int n0 = blockIdx.x * 128;
  const int m0 = blockIdx.y * 64;

  const int lrow8 = lane >> 3;
  const int gph8 = lane & 7;
  const int kg = (gph8 - lrow8) & 7;

  f32x4 zero = {0.f, 0.f, 0.f, 0.f};
  f32x4 acc[4][2];
#pragma unroll
  for (int i = 0; i < 4; ++i)
#pragma unroll
    for (int j = 0; j < 2; ++j) acc[i][j] = zero;

  for (int k0 = 0; k0 < E_DIM; k0 += 64) {
    __syncthreads();
    if (w < 2) {                    // stage A: 8 row-groups, 4 per wave
#pragma unroll
      for (int jj = 0; jj < 4; ++jj) {
        int j = w * 4 + jj;
        int r = j * 8 + lrow8;      // 0..63
        gl_lds16(attn + (size_t)(m0 + r) * E_DIM + k0 + kg * 8, Ah + j * 512);
      }
    } else {                        // stage W: 16 row-groups, 8 per wave
#pragma unroll
      for (int jj = 0; jj < 8; ++jj) {
        int j = (w - 2) * 8 + jj;
        int r = j * 8 + lrow8;      // 0..127
        gl_lds16(woh + (size_t)(n0 + r) * E_DIM + k0 + kg * 8, Wh + j * 512);
      }
    }
    __syncthreads();
#pragma unroll
    for (int ks = 0; ks < 2; ++ks) {
      short8 ahf[4];
#pragma unroll
      for (int i = 0; i < 4; ++i) {
        int r = i * 16 + l15;       // all 64 A-rows
        ahf[i] = *(const short8*)&Ah[r * 64 + ((ks * 4 + quad + r) & 7) * 8];
      }
#pragma unroll
      for (int j = 0; j < 2; ++j) {
        int r = w * 32 + j * 16 + l15;   // this wave's 32 W-rows
        short8 bhf = *(const short8*)&Wh[r * 64 + ((ks * 4 + quad + r) & 7) * 8];
#pragma unroll
        for (int i = 0; i < 4; ++i)
          acc[i][j] = __builtin_amdgcn_mfma_f32_16x16x32_f16(h8(ahf[i]), h8(bhf), acc[i][j], 0, 0, 0);
      }
    }
  }

#pragma unroll
  for (int j = 0; j < 2; ++j) {
    const int gc = n0 + w * 32 + j * 16 + l15;
    const float bb = bo[gc];
#pragma unroll
    for (int i = 0; i < 4; ++i)
#pragma unroll
      for (int reg = 0; reg < 4; ++reg) {
        const int gm = m0 + i * 16 + quad * 4 + reg;
        out[(size_t)gm * E_DIM + gc] = acc[i][j][reg] + bb;
      }
  }
}

// ---------------------------------------------------------------------------
// Flash attention v5 (round-2/6 verbatim, measured 51.3-52.0 us) — d-major V,
// ring3, vmcnt(4) waits, XCD remap, setprio. Counters pin this structure:
// MfmaUtil 38 + VALUBusy 35 from 2 waves/SIMD (grid-locked 2 blocks/CU);
// all QBLK/ring/layout neighbors measured worse (r1,r3,r4,r5). DO NOT TOUCH.
// ---------------------------------------------------------------------------
__global__ __launch_bounds__(256, 2) void attn_mfma(
    const short* __restrict__ q, const short* __restrict__ k,
    const short* __restrict__ vt, short* __restrict__ attn)
{
  __shared__ __align__(16) short SMEM[32768];   // 64 KB
  __shared__ float l_red[4][128];
  short* Qs = SMEM;            // 16 KB, dead after qa load
  short* KV = SMEM + 8192;     // ring[3] x wave[4] x (K 1024 + V 1024 shorts)

  const int tid = threadIdx.x;
  const int lane = tid & 63;
  const int w = tid >> 6;
  const int quad = lane >> 4;
  const int l15 = lane & 15;

  // XCD-aware remap: dispatch-linear id fid -> XCD fid%8.
  const int fid = blockIdx.y * 16 + blockIdx.x;
  const int bhid = fid & 31;
  const int t0 = (fid >> 5) * 128;
  const int b = bhid >> 4, h = bhid & 15;

  const short* qb = q + (size_t)bhid * T_DIM * 64;
  const short* kb = k + (size_t)bhid * T_DIM * 64;
  const short* vb = vt + (size_t)bhid * 64 * T_DIM;

  const int lrow8 = lane >> 3;
  const int gph8 = lane & 7;

  // ---- stage Q tile [128][64] ----
#pragma unroll
  for (int jj = 0; jj < 4; ++jj) {
    int j = w * 4 + jj;
    int r = j * 8 + lrow8;
    int gl = (gph8 - (r >> 1)) & 7;
    gl_lds16(qb + (size_t)(t0 + r) * 64 + gl * 8, Qs + j * 512);
  }

  // ---- stage K/V chunks 0,1 into rings 0,1 (wave-private slices) ----
  const int kg = (gph8 - lrow8) & 7;
  const int vd = lane >> 1, vh = lane & 1;
#pragma unroll
  for (int c0 = 0; c0 < 2; ++c0) {
    short* slot = KV + c0 * 8192 + w * 2048;
    const int sg = c0 * 64 + w * 16;
    gl_lds16(kb + (size_t)(sg + lrow8) * 64 + kg * 8, slot);
    gl_lds16(kb + (size_t)(sg + lrow8 + 8) * 64 + kg * 8, slot + 512);
    gl_lds16(vb + (size_t)vd * T_DIM + sg + vh * 8, slot + 1024);
    gl_lds16(vb + (size_t)(vd + 32) * T_DIM + sg + vh * 8, slot + 1536);
  }
  __syncthreads();

  // ---- register-cache Q B-fragments ----
  short8 qa[8][2];
#pragma unroll
  for (int qbk = 0; qbk < 8; ++qbk)
#pragma unroll
    for (int st = 0; st < 2; ++st) {
      int r = qbk * 16 + l15;
      int idx = r * 64 + (((st * 4 + quad) + (r >> 1)) & 7) * 8;
      qa[qbk][st] = *(const short8*)&Qs[idx];
    }

  f32x4 zero = {0.f, 0.f, 0.f, 0.f};
  f32x4 acc[4][8];               // [dblk][qbk] : O^T partial over own s-subset
  float l_part[8];
#pragma unroll
  for (int d = 0; d < 4; ++d)
#pragma unroll
    for (int qb2 = 0; qb2 < 8; ++qb2) acc[d][qb2] = zero;
#pragma unroll
  for (int i = 0; i < 8; ++i) l_part[i] = 0.f;

  for (int c = 0; c < 32; ++c) {
    if (c >= 2) {
      if (c == 31) __builtin_amdgcn_s_waitcnt(0x0F70);   // vmcnt(0)
      else         __builtin_amdgcn_s_waitcnt(0x0F74);   // vmcnt(4)
    }
    const short* slot = KV + (c % 3) * 8192 + w * 2048;

    short8 kf[2];
#pragma unroll
    for (int st = 0; st < 2; ++st)
      kf[st] = *(const short8*)&slot[l15 * 64 + (((st * 4 + quad) + l15) & 7) * 8];
    uint2 vfu[4];
#pragma unroll
    for (int dblk = 0; dblk < 4; ++dblk)
      vfu[dblk] = *(const uint2*)&slot[1024 + (dblk * 16 + l15) * 16 + quad * 4];

    if (c < 30) {
      short* nslot = KV + ((c + 2) % 3) * 8192 + w * 2048;
      const int sg = (c + 2) * 64 + w * 16;
      gl_lds16(kb + (size_t)(sg + lrow8) * 64 + kg * 8, nslot);
      gl_lds16(kb + (size_t)(sg + lrow8 + 8) * 64 + kg * 8, nslot + 512);
      gl_lds16(vb + (size_t)vd * T_DIM + sg + vh * 8, nslot + 1024);
      gl_lds16(vb + (size_t)(vd + 32) * T_DIM + sg + vh * 8, nslot + 1536);
    }

    __builtin_amdgcn_s_setprio(1);
    uint2 pb[8];
#pragma unroll
    for (int qbk = 0; qbk < 8; ++qbk) {
      f32x4 s = zero;
      s = __builtin_amdgcn_mfma_f32_16x16x32_f16(h8(kf[0]), h8(qa[qbk][0]), s, 0, 0, 0);
      s = __builtin_amdgcn_mfma_f32_16x16x32_f16(h8(kf[1]), h8(qa[qbk][1]), s, 0, 0, 0);
      float p0 = __builtin_amdgcn_exp2f(s[0]);
      float p1 = __builtin_amdgcn_exp2f(s[1]);
      float p2 = __builtin_amdgcn_exp2f(s[2]);
      float p3 = __builtin_amdgcn_exp2f(s[3]);
      l_part[qbk] += (p0 + p1) + (p2 + p3);
      pb[qbk].x = pk2(p0, p1);
      pb[qbk].y = pk2(p2, p3);
    }

#pragma unroll
    for (int dblk = 0; dblk < 4; ++dblk) {
      half4 va = __builtin_bit_cast(half4, vfu[dblk]);
#pragma unroll
      for (int qbk = 0; qbk < 8; ++qbk)
        acc[dblk][qbk] = __builtin_amdgcn_mfma_f32_16x16x16f16(
            va, __builtin_bit_cast(half4, pb[qbk]), acc[dblk][qbk], 0, 0, 0);
    }
    __builtin_amdgcn_s_setprio(0);
  }

  // ---- l reduce over quads, publish per-wave ----
#pragma unroll
  for (int qbk = 0; qbk < 8; ++qbk) {
    float l = l_part[qbk];
    l += __shfl_xor(l, 16);
    l += __shfl_xor(l, 32);
    if (quad == 0) l_red[w][qbk * 16 + l15] = l;
  }

  // ---- pairwise O reduce via 64 KB LDS scratch (overlays Qs+KV) ----
  f32x4* Osc = (f32x4*)SMEM;     // regions of 1024/2048 f32x4
  __syncthreads();               // all waves out of the main loop
  if (w & 1) {                   // w1 -> region0, w3 -> region1
    f32x4* dst = Osc + (w >> 1) * 2048;
#pragma unroll
    for (int dblk = 0; dblk < 4; ++dblk)
#pragma unroll
      for (int qbk = 0; qbk < 8; ++qbk)
        dst[(dblk * 8 + qbk) * 64 + lane] = acc[dblk][qbk];
  }
  __syncthreads();
  if (!(w & 1)) {                // w0 += region0 (all dblk), w2 += region1
    f32x4* src = Osc + (w >> 1) * 2048;
#pragma unroll
    for (int dblk = 0; dblk < 4; ++dblk)
#pragma unroll
      for (int qbk = 0; qbk < 8; ++qbk) {
        f32x4 t = src[(dblk * 8 + qbk) * 64 + lane];
        acc[dblk][qbk][0] += t[0]; acc[dblk][qbk][1] += t[1];
        acc[dblk][qbk][2] += t[2]; acc[dblk][qbk][3] += t[3];
      }
  }
  __syncthreads();
  // swap-publish: w2 gives its dblk 0,1 to w0; w0 gives its dblk 2,3 to w2
  if (w == 2) {
#pragma unroll
    for (int d2 = 0; d2 < 2; ++d2)
#pragma unroll
      for (int qbk = 0; qbk < 8; ++qbk)
        Osc[(d2 * 8 + qbk) * 64 + lane] = acc[d2][qbk];
  }
  if (w == 0) {
#pragma unroll
    for (int d2 = 0; d2 < 2; ++d2)
#pragma unroll
      for (int qbk = 0; qbk < 8; ++qbk)
        Osc[1024 + (d2 * 8 + qbk) * 64 + lane] = acc[2 + d2][qbk];
  }
  __syncthreads();
  if (w == 0) {                  // stores dblk 0,1
#pragma unroll
    for (int qbk = 0; qbk < 8; ++qbk) {
      const int qq = qbk * 16 + l15;
      const float lsum = l_red[0][qq] + l_red[1][qq] + l_red[2][qq] + l_red[3][qq];
      const float inv = 1.f / lsum;
      const int t = t0 + qq;
      const size_t mrow = (size_t)(t * 2 + b) * E_DIM;
#pragma unroll
      for (int d2 = 0; d2 < 2; ++d2) {
        f32x4 t4 = Osc[(d2 * 8 + qbk) * 64 + lane];
        uint2 ov;
        ov.x = pk2((acc[d2][qbk][0] + t4[0]) * inv, (acc[d2][qbk][1] + t4[1]) * inv);
        ov.y = pk2((acc[d2][qbk][2] + t4[2]) * inv, (acc[d2][qbk][3] + t4[3]) * inv);
        *(uint2*)&attn[mrow + h * 64 + d2 * 16 + quad * 4] = ov;
      }
    }
  }
  if (w == 2) {                  // stores dblk 2,3
#pragma unroll
    for (int qbk = 0; qbk < 8; ++qbk) {
      const int qq = qbk * 16 + l15;
      const float lsum = l_red[0][qq] + l_red[1][qq] + l_red[2][qq] + l_red[3][qq];
      const float inv = 1.f / lsum;
      const int t = t0 + qq;
      const size_t mrow = (size_t)(t * 2 + b) * E_DIM;
#pragma unroll
      for (int d2 = 0; d2 < 2; ++d2) {
        f32x4 t4 = Osc[1024 + (d2 * 8 + qbk) * 64 + lane];
        uint2 ov;
        ov.x = pk2((acc[2 + d2][qbk][0] + t4[0]) * inv, (acc[2 + d2][qbk][1] + t4[1]) * inv);
        ov.y = pk2((acc[2 + d2][qbk][2] + t4[2]) * inv, (acc[2 + d2][qbk][3] + t4[3]) * inv);
        *(uint2*)&attn[mrow + h * 64 + (2 + d2) * 16 + quad * 4] = ov;
      }
    }
  }
}

// ---------------------------------------------------------------------------
extern "C" void kernel_launch(void* const* d_in, const int* in_sizes, int n_in,
                              void* d_out, int out_size, void* d_ws, size_t ws_size,
                              hipStream_t stream)
{
  const float* x  = (const float*)d_in[0];
  const float* wq = (const float*)d_in[1];
  const float* bq = (const float*)d_in[2];
  const float* wk = (const float*)d_in[3];
  const float* bk = (const float*)d_in[4];
  const float* wv = (const float*)d_in[5];
  const float* bv = (const float*)d_in[6];
  const float* wo = (const float*)d_in[7];
  const float* bo = (const float*)d_in[8];
  float* out = (float*)d_out;

  short* ws = (short*)d_ws;
  const size_t M4 = (size_t)M_DIM * E_DIM;   // 4M elems
  const size_t M1 = (size_t)E_DIM * E_DIM;   // 1M elems
  short* aws  = ws;          // attn out fp16, live until gemm_out
  short* woh  = aws + M4;    // wo fp16, live until gemm_out
  short* xh   = woh + M1;
  short* wqh  = xh + M4;
  short* wkh  = wqh + M1;
  short* wvh  = wkh + M1;
  short* qws  = wvh + M1;
  short* kws  = qws + M4;
  short* vtws = kws + M4;    // end = 24M shorts = 48 MB

  convert_all<<<8192, 256, 0, stream>>>(x, wq, wk, wv, wo, xh, wqh, wkh, wvh, woh);
  gemm_qkv<<<dim3(24, 32), 512, 0, stream>>>(xh, wqh, wkh, wvh, bq, bk, bv,
                                             qws, kws, vtws);
  attn_mfma<<<dim3(16, 32), 256, 0, stream>>>(qws, kws, vtws, aws);
  gemm_out_v2<<<dim3(8, 64), 256, 0, stream>>>(aws, woh, bo, out);
}